// Round 4
// baseline (60618.848 us; speedup 1.0000x reference)
//
#include <hip/hip_runtime.h>
#include <math.h>

// NeuralCDE on MI355X. B=4096, SEQ=64 (63 segs), D=20, H=W=256, 126 RK4 steps.
// 256 WGs x 512 threads; each WG owns 16 batch rows for the whole integration.
// SPLIT-PRECISION: every matmul operand v = hi(fp16) + lo(fp16)/2048 (lo scaled
// x2048 to stay in fp16 normal range). C=A*B via 3 MFMAs (hi*hi; hi*lo'+lo'*hi
// in a second accumulator, rescaled at the end) -> ~22-bit operand precision,
// fp32 accumulate. Diagnostic for noise-vs-bug AND candidate final kernel.

typedef float f32x4 __attribute__((ext_vector_type(4)));
typedef _Float16 f16x8 __attribute__((ext_vector_type(8)));

#define MFMA16(a,b,c) __builtin_amdgcn_mfma_f32_16x16x32_f16((a),(b),(c),0,0,0)
#define INV2048 (4.8828125e-4f)

__device__ __forceinline__ unsigned short f2h(float f){
  _Float16 h = (_Float16)f;
  return __builtin_bit_cast(unsigned short, h);
}
__device__ __forceinline__ void split2(float v, unsigned short& hi, unsigned short& lo){
  _Float16 h = (_Float16)v;
  hi = __builtin_bit_cast(unsigned short, h);
  _Float16 l2 = (_Float16)((v - (float)h)*2048.f);
  lo = __builtin_bit_cast(unsigned short, l2);
}

// ---- prep: 256x256 fp32 -> fp16 hi/lo transpose: out*[n*256+k] = in[k*256+n]
__global__ void k_transpose256(const float* __restrict__ in,
                               unsigned short* __restrict__ ohi,
                               unsigned short* __restrict__ olo){
  int idx = blockIdx.x*256 + threadIdx.x;
  int n = idx>>8, k = idx&255;
  unsigned short h,l; split2(in[k*256+n], h, l);
  ohi[idx]=h; olo[idx]=l;
}

// ---- prep: W3 (256 x 5120) -> fragment-linearized fp16 hi/lo.
// flat = (((d*16+hb)*8+kc)*64+lane)*8+j ; value = W3[k][h*20+d],
// k = kc*32 + (lane>>4)*8 + j, h = hb*16 + (lane&15).
__global__ void k_w3prep(const float* __restrict__ w3,
                         unsigned short* __restrict__ ohi,
                         unsigned short* __restrict__ olo){
  int tid = blockIdx.x*256 + threadIdx.x;   // 1,310,720 total
  int j    = tid & 7;
  int lane = (tid>>3)&63;
  int kc   = (tid>>9)&7;
  int hb   = (tid>>12)&15;
  int d    = tid>>16;
  int k = kc*32 + (lane>>4)*8 + j;
  int h = hb*16 + (lane&15);
  unsigned short hh,ll; split2(w3[k*5120 + h*20 + d], hh, ll);
  ohi[tid]=hh; olo[tid]=ll;
}

__global__ __launch_bounds__(512) void k_main(
    const float* __restrict__ coeffs,
    const float* __restrict__ Wi,  const float* __restrict__ bi,
    const float* __restrict__ b1,  const float* __restrict__ b2,
    const float* __restrict__ b3,  const float* __restrict__ bs,
    const float* __restrict__ ln_g,const float* __restrict__ ln_b,
    const float* __restrict__ Winf,const float* __restrict__ binf,
    const float* __restrict__ Wdet,const float* __restrict__ bdet,
    const float* __restrict__ Wsur,const float* __restrict__ bsur,
    const unsigned short* __restrict__ W1Thi, const unsigned short* __restrict__ W1Tlo,
    const unsigned short* __restrict__ W2Thi, const unsigned short* __restrict__ W2Tlo,
    const unsigned short* __restrict__ WsThi, const unsigned short* __restrict__ WsTlo,
    const unsigned short* __restrict__ W3Lhi, const unsigned short* __restrict__ W3Llo,
    float* __restrict__ out)
{
  __shared__ unsigned short zs_hi[4096], zs_lo[4096];   // 16x256 fp16, XOR-swizzled
  __shared__ unsigned short h1_hi[4096], h1_lo[4096];
  __shared__ unsigned short h2_hi[4096], h2_lo[4096];
  __shared__ float dxt[2][20][16];          // double-buffered dX^T [d][m]
  __shared__ float hf[4096];                // head: h then r (fp32)

  const int tid = threadIdx.x;
  const int wv  = tid>>6;        // wave 0..7, owns cols [32*wv, 32*wv+32)
  const int l   = tid&63;
  const int l15 = l&15;
  const int mb  = l>>4;          // 0..3
  const int row0  = blockIdx.x*16;
  const int ncol0 = wv*32;

  float z[2][4], kacc[2][4], kst[2][4], zt[2][4];

  // ---------------- z0 = coeffs[:,0,:20] @ Wi + bi (fp32) ----------------
  {
    const float* cbase = coeffs + (size_t)(row0 + mb*4)*5040;
    for(int nfl=0; nfl<2; nfl++){
      int n = ncol0 + nfl*16 + l15;
      float a0=bi[n], a1=a0, a2=a0, a3=a0;
      for(int d=0; d<20; d++){
        float w = Wi[d*256+n];
        a0 += cbase[d         ]*w;
        a1 += cbase[d+1*5040  ]*w;
        a2 += cbase[d+2*5040  ]*w;
        a3 += cbase[d+3*5040  ]*w;
      }
      z[nfl][0]=a0; z[nfl][1]=a1; z[nfl][2]=a2; z[nfl][3]=a3;
    }
  }

  // lane's 8 (m,n) cells: m = mb*4+r (C/D row layout), n = ncol0+16*nfl+l15
  auto write_zs = [&](const float (&v)[2][4]){
    #pragma unroll
    for(int nfl=0; nfl<2; nfl++)
      #pragma unroll
      for(int r=0; r<4; r++){
        int m = mb*4+r;
        int n = ncol0 + nfl*16 + l15;
        int byte = ((m<<9) + (n<<1)) ^ ((m&7)<<4);
        unsigned short h,lw; split2(v[nfl][r], h, lw);
        *(unsigned short*)((char*)zs_hi + byte) = h;
        *(unsigned short*)((char*)zs_lo + byte) = lw;
      }
  };

  // A-fragment: row m = l15, k = kc*32 + mb*8 + j (same k-perm used for B)
  auto rdA = [&](const unsigned short* lds, int kc)->f16x8{
    int byte = ((l15<<9) + (kc<<6) + (mb<<4)) ^ ((l15&7)<<4);
    return *(const f16x8*)((const char*)lds + byte);
  };

  auto layer = [&](const unsigned short* shi, const unsigned short* slo,
                   unsigned short* dhi, unsigned short* dlo,
                   const unsigned short* __restrict__ WThi,
                   const unsigned short* __restrict__ WTlo,
                   const float* __restrict__ bias){
    f32x4 m0={0.f,0.f,0.f,0.f}, c0={0.f,0.f,0.f,0.f};
    f32x4 m1={0.f,0.f,0.f,0.f}, c1={0.f,0.f,0.f,0.f};
    const int off0 = (ncol0+l15)*256 + mb*8;
    const int off1 = off0 + 16*256;
    #pragma unroll
    for(int kc=0; kc<8; kc++){
      f16x8 ah = rdA(shi, kc), al = rdA(slo, kc);
      f16x8 b0h = *(const f16x8*)(WThi + off0 + kc*32);
      f16x8 b0l = *(const f16x8*)(WTlo + off0 + kc*32);
      f16x8 b1h = *(const f16x8*)(WThi + off1 + kc*32);
      f16x8 b1l = *(const f16x8*)(WTlo + off1 + kc*32);
      m0 = MFMA16(ah, b0h, m0);
      c0 = MFMA16(ah, b0l, c0);
      c0 = MFMA16(al, b0h, c0);
      m1 = MFMA16(ah, b1h, m1);
      c1 = MFMA16(ah, b1l, c1);
      c1 = MFMA16(al, b1h, c1);
    }
    float bb0 = bias[ncol0+l15], bb1 = bias[ncol0+16+l15];
    #pragma unroll
    for(int r=0; r<4; r++){
      int m = mb*4+r;
      int b0a = ((m<<9) + ((ncol0+l15)<<1))    ^ ((m&7)<<4);
      int b1a = ((m<<9) + ((ncol0+16+l15)<<1)) ^ ((m&7)<<4);
      float v0 = tanhf(m0[r] + c0[r]*INV2048 + bb0);
      float v1 = tanhf(m1[r] + c1[r]*INV2048 + bb1);
      unsigned short h,lw;
      split2(v0,h,lw);
      *(unsigned short*)((char*)dhi + b0a) = h;
      *(unsigned short*)((char*)dlo + b0a) = lw;
      split2(v1,h,lw);
      *(unsigned short*)((char*)dhi + b1a) = h;
      *(unsigned short*)((char*)dlo + b1a) = lw;
    }
  };

  // vf = sum_d dX[:,d] * (h2 @ W3_d + b3_d); dX scale applied on output frags
  auto vf_eval = [&](int par){
    f16x8 Ah[8], Al[8];
    #pragma unroll
    for(int kc=0; kc<8; kc++){ Ah[kc] = rdA(h2_hi, kc); Al[kc] = rdA(h2_lo, kc); }
    #pragma unroll
    for(int nfl=0; nfl<2; nfl++)
      #pragma unroll
      for(int r=0; r<4; r++) kst[nfl][r] = 0.f;
    const int hb0 = wv*2;
    for(int d=0; d<20; d++){
      f32x4 dxv = *(const f32x4*)&dxt[par][d][mb*4];
      #pragma unroll
      for(int nfl=0; nfl<2; nfl++){
        const size_t base = ((size_t)(d*16 + hb0 + nfl))*4096 + l*8;
        const unsigned short* wh = W3Lhi + base;
        const unsigned short* wl = W3Llo + base;
        f32x4 tm = {0.f,0.f,0.f,0.f}, tc = {0.f,0.f,0.f,0.f};
        #pragma unroll
        for(int kc=0; kc<8; kc++){
          f16x8 bh = *(const f16x8*)(wh + kc*512);
          f16x8 bl = *(const f16x8*)(wl + kc*512);
          tm = MFMA16(Ah[kc], bh, tm);
          tc = MFMA16(Ah[kc], bl, tc);
          tc = MFMA16(Al[kc], bh, tc);
        }
        int h = ncol0 + nfl*16 + l15;
        float b3v = b3[h*20 + d];
        #pragma unroll
        for(int r=0; r<4; r++)
          kst[nfl][r] += dxv[r]*(tm[r] + tc[r]*INV2048 + b3v);
      }
    }
  };

  // q = time in quarter-steps (exact): i = min(q>>2, 62), u = 0.25*(q-4i)
  auto compute_dx = [&](int q, int par){
    if(tid < 320){
      int m = tid/20, d = tid - m*20;
      int i = q>>2; if(i>62) i = 62;
      float u = 0.25f*(float)(q - 4*i);
      const float* seg = coeffs + (size_t)(row0+m)*5040 + i*80;
      dxt[par][d][m] = seg[20+d] + 2.f*seg[40+d]*u + 3.f*seg[60+d]*(u*u);
    }
  };

  auto run_layers = [&](){
    __syncthreads();                 // zs + dxt written earlier now visible
    layer(zs_hi, zs_lo, h1_hi, h1_lo, W1Thi, W1Tlo, b1);
    __syncthreads();
    layer(h1_hi, h1_lo, h2_hi, h2_lo, W2Thi, W2Tlo, b2);
    __syncthreads();
  };

  write_zs(z);
  compute_dx(0, 0);

  for(int k=0; k<126; k++){
    int q0 = 2*k;
    // stage 1: dX(q0) in dxt[0] (from init / prev stage 4)
    compute_dx(q0+1, 1);
    run_layers();
    vf_eval(0);
    #pragma unroll
    for(int f=0; f<2; f++)
      #pragma unroll
      for(int r=0; r<4; r++){ float kv=kst[f][r]; kacc[f][r]=kv; zt[f][r]=z[f][r]+0.25f*kv; }
    write_zs(zt);
    // stage 2: dX(q0+1) in dxt[1]
    run_layers();
    vf_eval(1);
    #pragma unroll
    for(int f=0; f<2; f++)
      #pragma unroll
      for(int r=0; r<4; r++){ float kv=kst[f][r]; kacc[f][r]+=2.f*kv; zt[f][r]=z[f][r]+0.25f*kv; }
    write_zs(zt);
    // stage 3: same dX as stage 2
    compute_dx(q0+2, 0);
    run_layers();
    vf_eval(1);
    #pragma unroll
    for(int f=0; f<2; f++)
      #pragma unroll
      for(int r=0; r<4; r++){ float kv=kst[f][r]; kacc[f][r]+=2.f*kv; zt[f][r]=z[f][r]+0.5f*kv; }
    write_zs(zt);
    // stage 4: dX(q0+2) in dxt[0]  (reused as next step's stage-1 dX)
    run_layers();
    vf_eval(0);
    #pragma unroll
    for(int f=0; f<2; f++)
      #pragma unroll
      for(int r=0; r<4; r++) z[f][r] += (1.f/12.f)*(kacc[f][r] + kst[f][r]);
    write_zs(z);
  }

  // ---------------- head: h = z@Ws + bs (split) ----------------
  __syncthreads();
  {
    f32x4 m0={0.f,0.f,0.f,0.f}, c0={0.f,0.f,0.f,0.f};
    f32x4 m1={0.f,0.f,0.f,0.f}, c1={0.f,0.f,0.f,0.f};
    const int off0 = (ncol0+l15)*256 + mb*8;
    const int off1 = off0 + 16*256;
    #pragma unroll
    for(int kc=0; kc<8; kc++){
      f16x8 ah = rdA(zs_hi, kc), al = rdA(zs_lo, kc);
      f16x8 b0h = *(const f16x8*)(WsThi + off0 + kc*32);
      f16x8 b0l = *(const f16x8*)(WsTlo + off0 + kc*32);
      f16x8 b1h = *(const f16x8*)(WsThi + off1 + kc*32);
      f16x8 b1l = *(const f16x8*)(WsTlo + off1 + kc*32);
      m0 = MFMA16(ah, b0h, m0);
      c0 = MFMA16(ah, b0l, c0);
      c0 = MFMA16(al, b0h, c0);
      m1 = MFMA16(ah, b1h, m1);
      c1 = MFMA16(ah, b1l, c1);
      c1 = MFMA16(al, b1h, c1);
    }
    float bb0 = bs[ncol0+l15], bb1 = bs[ncol0+16+l15];
    #pragma unroll
    for(int r=0; r<4; r++){
      int m = mb*4+r;
      hf[m*256 + ncol0+l15]    = m0[r] + c0[r]*INV2048 + bb0;
      hf[m*256 + ncol0+16+l15] = m1[r] + c1[r]*INV2048 + bb1;
    }
  }
  __syncthreads();
  // LayerNorm + relu; wave handles rows 2wv, 2wv+1 (32 lanes per row)
  {
    int m  = 2*wv + (l>>5);
    int j0 = (l&31)*8;
    float v[8]; float s=0.f, s2=0.f;
    #pragma unroll
    for(int j=0; j<8; j++){ v[j] = hf[m*256+j0+j]; s += v[j]; }
    #pragma unroll
    for(int off=16; off>=1; off>>=1) s += __shfl_xor(s, off);
    float mu = s*(1.f/256.f);
    #pragma unroll
    for(int j=0; j<8; j++){ float dm = v[j]-mu; s2 += dm*dm; }
    #pragma unroll
    for(int off=16; off>=1; off>>=1) s2 += __shfl_xor(s2, off);
    float rs = rsqrtf(s2*(1.f/256.f) + 1e-5f);
    #pragma unroll
    for(int j=0; j<8; j++){
      float rv = ln_g[j0+j]*((v[j]-mu)*rs) + ln_b[j0+j];
      rv = fmaxf(rv, 0.f);
      hf[m*256+j0+j] = rv;                                  // r for heads
      out[36864 + (size_t)(row0+m)*256 + j0 + j] = rv;      // r output (fp32)
    }
  }
  __syncthreads();
  // heads: 16 rows x 9 logits (4 inf, 3 det, 2 sur)
  if(tid < 144){
    int m = tid/9, jj = tid - m*9;
    const float* Wh; float bv; int stride;
    if(jj<4){ Wh = Winf + jj;     stride=4; bv = binf[jj];   }
    else if(jj<7){ Wh = Wdet + (jj-4); stride=3; bv = bdet[jj-4]; }
    else { Wh = Wsur + (jj-7); stride=2; bv = bsur[jj-7]; }
    float acc = bv;
    const float* hr = &hf[m*256];
    for(int kk=0; kk<256; kk++) acc += hr[kk]*Wh[kk*stride];
    if(jj<4){
      out[(size_t)(row0+m)*4 + jj] = 1.f/(1.f+expf(-acc));
    } else if(jj<7){
      out[16384 + (size_t)(row0+m)*3 + (jj-4)] = 1.f/(1.f+expf(-acc));
    } else {
      // softplus = logaddexp(x,0), numerically stable
      out[28672 + (size_t)(row0+m)*2 + (jj-7)] = fmaxf(acc,0.f) + log1pf(expf(-fabsf(acc)));
    }
  }
}

extern "C" void kernel_launch(void* const* d_in, const int* in_sizes, int n_in,
                              void* d_out, int out_size, void* d_ws, size_t ws_size,
                              hipStream_t stream)
{
  const float* coeffs = (const float*)d_in[0];
  const float* Wi   = (const float*)d_in[1];
  const float* bi   = (const float*)d_in[2];
  const float* W1   = (const float*)d_in[3];
  const float* b1   = (const float*)d_in[4];
  const float* W2   = (const float*)d_in[5];
  const float* b2   = (const float*)d_in[6];
  const float* W3   = (const float*)d_in[7];
  const float* b3   = (const float*)d_in[8];
  const float* Ws   = (const float*)d_in[9];
  const float* bs   = (const float*)d_in[10];
  const float* ln_g = (const float*)d_in[11];
  const float* ln_b = (const float*)d_in[12];
  const float* Winf = (const float*)d_in[13];
  const float* binf = (const float*)d_in[14];
  const float* Wdet = (const float*)d_in[15];
  const float* bdet = (const float*)d_in[16];
  const float* Wsur = (const float*)d_in[17];
  const float* bsur = (const float*)d_in[18];

  unsigned short* W1Thi = (unsigned short*)d_ws;
  unsigned short* W1Tlo = W1Thi + 65536;
  unsigned short* W2Thi = W1Tlo + 65536;
  unsigned short* W2Tlo = W2Thi + 65536;
  unsigned short* WsThi = W2Tlo + 65536;
  unsigned short* WsTlo = WsThi + 65536;
  unsigned short* W3Lhi = WsTlo + 65536;
  unsigned short* W3Llo = W3Lhi + 1310720;
  float* out = (float*)d_out;

  k_transpose256<<<256, 256, 0, stream>>>(W1, W1Thi, W1Tlo);
  k_transpose256<<<256, 256, 0, stream>>>(W2, W2Thi, W2Tlo);
  k_transpose256<<<256, 256, 0, stream>>>(Ws, WsThi, WsTlo);
  k_w3prep<<<5120, 256, 0, stream>>>(W3, W3Lhi, W3Llo);
  k_main<<<256, 512, 0, stream>>>(coeffs, Wi, bi, b1, b2, b3, bs, ln_g, ln_b,
                                  Winf, binf, Wdet, bdet, Wsur, bsur,
                                  W1Thi, W1Tlo, W2Thi, W2Tlo, WsThi, WsTlo,
                                  W3Lhi, W3Llo, out);
}

// Round 5
// 36028.809 us; speedup vs baseline: 1.6825x; 1.6825x over previous
//
#include <hip/hip_runtime.h>
#include <math.h>

// NeuralCDE on MI355X. B=4096, SEQ=64 (63 segs), D=20, H=W=256, 126 RK4 steps.
// 256 WGs x 512 threads (1 WG/CU); each WG owns 16 batch rows for the whole
// integration. SPLIT-PRECISION fp16 hi/lo (lo scaled x2048): 3 MFMAs per tile
// -> ~22-bit operand precision, fp32 accumulate. absmax 0.043 (r4, passing).
// r5 change: __launch_bounds__(512,2) frees a 256-VGPR budget (occupancy is
// pinned at 8 waves/CU by grid=1WG/CU anyway) + explicit ping-pong register
// double-buffer of W3 fragments in vf_eval so L2 latency hides under MFMAs.

typedef float f32x4 __attribute__((ext_vector_type(4)));
typedef _Float16 f16x8 __attribute__((ext_vector_type(8)));

#define MFMA16(a,b,c) __builtin_amdgcn_mfma_f32_16x16x32_f16((a),(b),(c),0,0,0)
#define INV2048 (4.8828125e-4f)

__device__ __forceinline__ unsigned short f2h(float f){
  _Float16 h = (_Float16)f;
  return __builtin_bit_cast(unsigned short, h);
}
__device__ __forceinline__ void split2(float v, unsigned short& hi, unsigned short& lo){
  _Float16 h = (_Float16)v;
  hi = __builtin_bit_cast(unsigned short, h);
  _Float16 l2 = (_Float16)((v - (float)h)*2048.f);
  lo = __builtin_bit_cast(unsigned short, l2);
}

// ---- prep: 256x256 fp32 -> fp16 hi/lo transpose: out*[n*256+k] = in[k*256+n]
__global__ void k_transpose256(const float* __restrict__ in,
                               unsigned short* __restrict__ ohi,
                               unsigned short* __restrict__ olo){
  int idx = blockIdx.x*256 + threadIdx.x;
  int n = idx>>8, k = idx&255;
  unsigned short h,l; split2(in[k*256+n], h, l);
  ohi[idx]=h; olo[idx]=l;
}

// ---- prep: W3 (256 x 5120) -> fragment-linearized fp16 hi/lo.
// flat = (((d*16+hb)*8+kc)*64+lane)*8+j ; value = W3[k][h*20+d],
// k = kc*32 + (lane>>4)*8 + j, h = hb*16 + (lane&15).
__global__ void k_w3prep(const float* __restrict__ w3,
                         unsigned short* __restrict__ ohi,
                         unsigned short* __restrict__ olo){
  int tid = blockIdx.x*256 + threadIdx.x;   // 1,310,720 total
  int j    = tid & 7;
  int lane = (tid>>3)&63;
  int kc   = (tid>>9)&7;
  int hb   = (tid>>12)&15;
  int d    = tid>>16;
  int k = kc*32 + (lane>>4)*8 + j;
  int h = hb*16 + (lane&15);
  unsigned short hh,ll; split2(w3[k*5120 + h*20 + d], hh, ll);
  ohi[tid]=hh; olo[tid]=ll;
}

__global__ __launch_bounds__(512, 2) void k_main(
    const float* __restrict__ coeffs,
    const float* __restrict__ Wi,  const float* __restrict__ bi,
    const float* __restrict__ b1,  const float* __restrict__ b2,
    const float* __restrict__ b3,  const float* __restrict__ bs,
    const float* __restrict__ ln_g,const float* __restrict__ ln_b,
    const float* __restrict__ Winf,const float* __restrict__ binf,
    const float* __restrict__ Wdet,const float* __restrict__ bdet,
    const float* __restrict__ Wsur,const float* __restrict__ bsur,
    const unsigned short* __restrict__ W1Thi, const unsigned short* __restrict__ W1Tlo,
    const unsigned short* __restrict__ W2Thi, const unsigned short* __restrict__ W2Tlo,
    const unsigned short* __restrict__ WsThi, const unsigned short* __restrict__ WsTlo,
    const unsigned short* __restrict__ W3Lhi, const unsigned short* __restrict__ W3Llo,
    float* __restrict__ out)
{
  __shared__ unsigned short zs_hi[4096], zs_lo[4096];   // 16x256 fp16, XOR-swizzled
  __shared__ unsigned short h1_hi[4096], h1_lo[4096];
  __shared__ unsigned short h2_hi[4096], h2_lo[4096];
  __shared__ float dxt[2][20][16];          // double-buffered dX^T [d][m]
  __shared__ float hf[4096];                // head: h then r (fp32)

  const int tid = threadIdx.x;
  const int wv  = tid>>6;        // wave 0..7, owns cols [32*wv, 32*wv+32)
  const int l   = tid&63;
  const int l15 = l&15;
  const int mb  = l>>4;          // 0..3
  const int row0  = blockIdx.x*16;
  const int ncol0 = wv*32;

  float z[2][4], kacc[2][4], kst[2][4], zt[2][4];

  // ---------------- z0 = coeffs[:,0,:20] @ Wi + bi (fp32) ----------------
  {
    const float* cbase = coeffs + (size_t)(row0 + mb*4)*5040;
    for(int nfl=0; nfl<2; nfl++){
      int n = ncol0 + nfl*16 + l15;
      float a0=bi[n], a1=a0, a2=a0, a3=a0;
      for(int d=0; d<20; d++){
        float w = Wi[d*256+n];
        a0 += cbase[d         ]*w;
        a1 += cbase[d+1*5040  ]*w;
        a2 += cbase[d+2*5040  ]*w;
        a3 += cbase[d+3*5040  ]*w;
      }
      z[nfl][0]=a0; z[nfl][1]=a1; z[nfl][2]=a2; z[nfl][3]=a3;
    }
  }

  // lane's 8 (m,n) cells: m = mb*4+r (C/D row layout), n = ncol0+16*nfl+l15
  auto write_zs = [&](const float (&v)[2][4]){
    #pragma unroll
    for(int nfl=0; nfl<2; nfl++)
      #pragma unroll
      for(int r=0; r<4; r++){
        int m = mb*4+r;
        int n = ncol0 + nfl*16 + l15;
        int byte = ((m<<9) + (n<<1)) ^ ((m&7)<<4);
        unsigned short h,lw; split2(v[nfl][r], h, lw);
        *(unsigned short*)((char*)zs_hi + byte) = h;
        *(unsigned short*)((char*)zs_lo + byte) = lw;
      }
  };

  // A-fragment: row m = l15, k = kc*32 + mb*8 + j (same k-perm used for B)
  auto rdA = [&](const unsigned short* lds, int kc)->f16x8{
    int byte = ((l15<<9) + (kc<<6) + (mb<<4)) ^ ((l15&7)<<4);
    return *(const f16x8*)((const char*)lds + byte);
  };

  auto layer = [&](const unsigned short* shi, const unsigned short* slo,
                   unsigned short* dhi, unsigned short* dlo,
                   const unsigned short* __restrict__ WThi,
                   const unsigned short* __restrict__ WTlo,
                   const float* __restrict__ bias){
    f32x4 m0={0.f,0.f,0.f,0.f}, c0={0.f,0.f,0.f,0.f};
    f32x4 m1={0.f,0.f,0.f,0.f}, c1={0.f,0.f,0.f,0.f};
    const int off0 = (ncol0+l15)*256 + mb*8;
    const int off1 = off0 + 16*256;
    #pragma unroll
    for(int kc=0; kc<8; kc++){
      f16x8 ah = rdA(shi, kc), al = rdA(slo, kc);
      f16x8 b0h = *(const f16x8*)(WThi + off0 + kc*32);
      f16x8 b0l = *(const f16x8*)(WTlo + off0 + kc*32);
      f16x8 b1h = *(const f16x8*)(WThi + off1 + kc*32);
      f16x8 b1l = *(const f16x8*)(WTlo + off1 + kc*32);
      m0 = MFMA16(ah, b0h, m0);
      c0 = MFMA16(ah, b0l, c0);
      c0 = MFMA16(al, b0h, c0);
      m1 = MFMA16(ah, b1h, m1);
      c1 = MFMA16(ah, b1l, c1);
      c1 = MFMA16(al, b1h, c1);
    }
    float bb0 = bias[ncol0+l15], bb1 = bias[ncol0+16+l15];
    #pragma unroll
    for(int r=0; r<4; r++){
      int m = mb*4+r;
      int b0a = ((m<<9) + ((ncol0+l15)<<1))    ^ ((m&7)<<4);
      int b1a = ((m<<9) + ((ncol0+16+l15)<<1)) ^ ((m&7)<<4);
      float v0 = tanhf(m0[r] + c0[r]*INV2048 + bb0);
      float v1 = tanhf(m1[r] + c1[r]*INV2048 + bb1);
      unsigned short h,lw;
      split2(v0,h,lw);
      *(unsigned short*)((char*)dhi + b0a) = h;
      *(unsigned short*)((char*)dlo + b0a) = lw;
      split2(v1,h,lw);
      *(unsigned short*)((char*)dhi + b1a) = h;
      *(unsigned short*)((char*)dlo + b1a) = lw;
    }
  };

  // vf = sum_d dX[:,d] * (h2 @ W3_d + b3_d); dX scale applied on output frags.
  // Explicit ping-pong register double-buffer over the 40 (d,nfl) chunks:
  // issue chunk i+1/i+2 loads while chunk i's 24 MFMAs run (L2 latency hiding).
  auto vf_eval = [&](int par){
    f16x8 Ah[8], Al[8];
    #pragma unroll
    for(int kc=0; kc<8; kc++){ Ah[kc] = rdA(h2_hi, kc); Al[kc] = rdA(h2_lo, kc); }
    #pragma unroll
    for(int nfl=0; nfl<2; nfl++)
      #pragma unroll
      for(int r=0; r<4; r++) kst[nfl][r] = 0.f;
    const int hb0 = wv*2;
    const unsigned short* wbh = W3Lhi + ((size_t)hb0*8)*512 + l*8;
    const unsigned short* wbl = W3Llo + ((size_t)hb0*8)*512 + l*8;

    f16x8 ah_[8], al_[8], bh_[8], bl_[8];   // ping-pong buffers (static idx only)

    // issue 16 fragment loads for chunk it = d*2+nfl into the given buffers
    auto issue = [&](int it, f16x8* BH, f16x8* BL){
      int d = it>>1, nfl = it&1;
      size_t off = ((size_t)d*16 + nfl)*4096;
      #pragma unroll
      for(int kc=0; kc<8; kc++){
        BH[kc] = *(const f16x8*)(wbh + off + kc*512);
        BL[kc] = *(const f16x8*)(wbl + off + kc*512);
      }
    };
    // 24 MFMAs + accumulate for chunk (d, nfl_c) [nfl_c is a compile-time 0/1]
    auto consume = [&](int d, int nfl_c, const f16x8* BH, const f16x8* BL){
      f32x4 tm = {0.f,0.f,0.f,0.f}, tc = {0.f,0.f,0.f,0.f};
      #pragma unroll
      for(int kc=0; kc<8; kc++){
        tm = MFMA16(Ah[kc], BH[kc], tm);
        tc = MFMA16(Ah[kc], BL[kc], tc);
        tc = MFMA16(Al[kc], BH[kc], tc);
      }
      f32x4 dxv = *(const f32x4*)&dxt[par][d][mb*4];
      int h = ncol0 + nfl_c*16 + l15;
      float b3v = b3[h*20 + d];
      #pragma unroll
      for(int r=0; r<4; r++)
        kst[nfl_c][r] += dxv[r]*(tm[r] + tc[r]*INV2048 + b3v);
    };

    issue(0, ah_, al_);
    #pragma unroll 1
    for(int it=0; it<40; it+=2){
      int d = it>>1;
      issue(it+1, bh_, bl_);            // it+1 <= 39 always
      consume(d, 0, ah_, al_);
      if(it+2<40) issue(it+2, ah_, al_);
      consume(d, 1, bh_, bl_);
    }
  };

  // q = time in quarter-steps (exact): i = min(q>>2, 62), u = 0.25*(q-4i)
  auto compute_dx = [&](int q, int par){
    if(tid < 320){
      int m = tid/20, d = tid - m*20;
      int i = q>>2; if(i>62) i = 62;
      float u = 0.25f*(float)(q - 4*i);
      const float* seg = coeffs + (size_t)(row0+m)*5040 + i*80;
      dxt[par][d][m] = seg[20+d] + 2.f*seg[40+d]*u + 3.f*seg[60+d]*(u*u);
    }
  };

  auto run_layers = [&](){
    __syncthreads();                 // zs + dxt written earlier now visible
    layer(zs_hi, zs_lo, h1_hi, h1_lo, W1Thi, W1Tlo, b1);
    __syncthreads();
    layer(h1_hi, h1_lo, h2_hi, h2_lo, W2Thi, W2Tlo, b2);
    __syncthreads();
  };

  write_zs(z);
  compute_dx(0, 0);

  for(int k=0; k<126; k++){
    int q0 = 2*k;
    // stage 1: dX(q0) in dxt[0] (from init / prev stage 4)
    compute_dx(q0+1, 1);
    run_layers();
    vf_eval(0);
    #pragma unroll
    for(int f=0; f<2; f++)
      #pragma unroll
      for(int r=0; r<4; r++){ float kv=kst[f][r]; kacc[f][r]=kv; zt[f][r]=z[f][r]+0.25f*kv; }
    write_zs(zt);
    // stage 2: dX(q0+1) in dxt[1]
    run_layers();
    vf_eval(1);
    #pragma unroll
    for(int f=0; f<2; f++)
      #pragma unroll
      for(int r=0; r<4; r++){ float kv=kst[f][r]; kacc[f][r]+=2.f*kv; zt[f][r]=z[f][r]+0.25f*kv; }
    write_zs(zt);
    // stage 3: same dX as stage 2
    compute_dx(q0+2, 0);
    run_layers();
    vf_eval(1);
    #pragma unroll
    for(int f=0; f<2; f++)
      #pragma unroll
      for(int r=0; r<4; r++){ float kv=kst[f][r]; kacc[f][r]+=2.f*kv; zt[f][r]=z[f][r]+0.5f*kv; }
    write_zs(zt);
    // stage 4: dX(q0+2) in dxt[0]  (reused as next step's stage-1 dX)
    run_layers();
    vf_eval(0);
    #pragma unroll
    for(int f=0; f<2; f++)
      #pragma unroll
      for(int r=0; r<4; r++) z[f][r] += (1.f/12.f)*(kacc[f][r] + kst[f][r]);
    write_zs(z);
  }

  // ---------------- head: h = z@Ws + bs (split) ----------------
  __syncthreads();
  {
    f32x4 m0={0.f,0.f,0.f,0.f}, c0={0.f,0.f,0.f,0.f};
    f32x4 m1={0.f,0.f,0.f,0.f}, c1={0.f,0.f,0.f,0.f};
    const int off0 = (ncol0+l15)*256 + mb*8;
    const int off1 = off0 + 16*256;
    #pragma unroll
    for(int kc=0; kc<8; kc++){
      f16x8 ah = rdA(zs_hi, kc), al = rdA(zs_lo, kc);
      f16x8 b0h = *(const f16x8*)(WsThi + off0 + kc*32);
      f16x8 b0l = *(const f16x8*)(WsTlo + off0 + kc*32);
      f16x8 b1h = *(const f16x8*)(WsThi + off1 + kc*32);
      f16x8 b1l = *(const f16x8*)(WsTlo + off1 + kc*32);
      m0 = MFMA16(ah, b0h, m0);
      c0 = MFMA16(ah, b0l, c0);
      c0 = MFMA16(al, b0h, c0);
      m1 = MFMA16(ah, b1h, m1);
      c1 = MFMA16(ah, b1l, c1);
      c1 = MFMA16(al, b1h, c1);
    }
    float bb0 = bs[ncol0+l15], bb1 = bs[ncol0+16+l15];
    #pragma unroll
    for(int r=0; r<4; r++){
      int m = mb*4+r;
      hf[m*256 + ncol0+l15]    = m0[r] + c0[r]*INV2048 + bb0;
      hf[m*256 + ncol0+16+l15] = m1[r] + c1[r]*INV2048 + bb1;
    }
  }
  __syncthreads();
  // LayerNorm + relu; wave handles rows 2wv, 2wv+1 (32 lanes per row)
  {
    int m  = 2*wv + (l>>5);
    int j0 = (l&31)*8;
    float v[8]; float s=0.f, s2=0.f;
    #pragma unroll
    for(int j=0; j<8; j++){ v[j] = hf[m*256+j0+j]; s += v[j]; }
    #pragma unroll
    for(int off=16; off>=1; off>>=1) s += __shfl_xor(s, off);
    float mu = s*(1.f/256.f);
    #pragma unroll
    for(int j=0; j<8; j++){ float dm = v[j]-mu; s2 += dm*dm; }
    #pragma unroll
    for(int off=16; off>=1; off>>=1) s2 += __shfl_xor(s2, off);
    float rs = rsqrtf(s2*(1.f/256.f) + 1e-5f);
    #pragma unroll
    for(int j=0; j<8; j++){
      float rv = ln_g[j0+j]*((v[j]-mu)*rs) + ln_b[j0+j];
      rv = fmaxf(rv, 0.f);
      hf[m*256+j0+j] = rv;                                  // r for heads
      out[36864 + (size_t)(row0+m)*256 + j0 + j] = rv;      // r output (fp32)
    }
  }
  __syncthreads();
  // heads: 16 rows x 9 logits (4 inf, 3 det, 2 sur)
  if(tid < 144){
    int m = tid/9, jj = tid - m*9;
    const float* Wh; float bv; int stride;
    if(jj<4){ Wh = Winf + jj;     stride=4; bv = binf[jj];   }
    else if(jj<7){ Wh = Wdet + (jj-4); stride=3; bv = bdet[jj-4]; }
    else { Wh = Wsur + (jj-7); stride=2; bv = bsur[jj-7]; }
    float acc = bv;
    const float* hr = &hf[m*256];
    for(int kk=0; kk<256; kk++) acc += hr[kk]*Wh[kk*stride];
    if(jj<4){
      out[(size_t)(row0+m)*4 + jj] = 1.f/(1.f+expf(-acc));
    } else if(jj<7){
      out[16384 + (size_t)(row0+m)*3 + (jj-4)] = 1.f/(1.f+expf(-acc));
    } else {
      // softplus = logaddexp(x,0), numerically stable
      out[28672 + (size_t)(row0+m)*2 + (jj-7)] = fmaxf(acc,0.f) + log1pf(expf(-fabsf(acc)));
    }
  }
}

extern "C" void kernel_launch(void* const* d_in, const int* in_sizes, int n_in,
                              void* d_out, int out_size, void* d_ws, size_t ws_size,
                              hipStream_t stream)
{
  const float* coeffs = (const float*)d_in[0];
  const float* Wi   = (const float*)d_in[1];
  const float* bi   = (const float*)d_in[2];
  const float* W1   = (const float*)d_in[3];
  const float* b1   = (const float*)d_in[4];
  const float* W2   = (const float*)d_in[5];
  const float* b2   = (const float*)d_in[6];
  const float* W3   = (const float*)d_in[7];
  const float* b3   = (const float*)d_in[8];
  const float* Ws   = (const float*)d_in[9];
  const float* bs   = (const float*)d_in[10];
  const float* ln_g = (const float*)d_in[11];
  const float* ln_b = (const float*)d_in[12];
  const float* Winf = (const float*)d_in[13];
  const float* binf = (const float*)d_in[14];
  const float* Wdet = (const float*)d_in[15];
  const float* bdet = (const float*)d_in[16];
  const float* Wsur = (const float*)d_in[17];
  const float* bsur = (const float*)d_in[18];

  unsigned short* W1Thi = (unsigned short*)d_ws;
  unsigned short* W1Tlo = W1Thi + 65536;
  unsigned short* W2Thi = W1Tlo + 65536;
  unsigned short* W2Tlo = W2Thi + 65536;
  unsigned short* WsThi = W2Tlo + 65536;
  unsigned short* WsTlo = WsThi + 65536;
  unsigned short* W3Lhi = WsTlo + 65536;
  unsigned short* W3Llo = W3Lhi + 1310720;
  float* out = (float*)d_out;

  k_transpose256<<<256, 256, 0, stream>>>(W1, W1Thi, W1Tlo);
  k_transpose256<<<256, 256, 0, stream>>>(W2, W2Thi, W2Tlo);
  k_transpose256<<<256, 256, 0, stream>>>(Ws, WsThi, WsTlo);
  k_w3prep<<<5120, 256, 0, stream>>>(W3, W3Lhi, W3Llo);
  k_main<<<256, 512, 0, stream>>>(coeffs, Wi, bi, b1, b2, b3, bs, ln_g, ln_b,
                                  Winf, binf, Wdet, bdet, Wsur, bsur,
                                  W1Thi, W1Tlo, W2Thi, W2Tlo, WsThi, WsTlo,
                                  W3Lhi, W3Llo, out);
}